// Round 6
// baseline (82.241 us; speedup 1.0000x reference)
//
#include <hip/hip_runtime.h>

#define B 8
#define N 512
#define D 128
#define H 128
#define IC 16     // i-rows per block (pair kernel)
#define JT 64     // j-cols per block (4 waves x 16)

typedef __attribute__((ext_vector_type(8))) _Float16 f16x8;
typedef __attribute__((ext_vector_type(4))) float f32x4;

union F8 { uint4 u; f16x8 f; };

// ---------------- kernel 0: build Wpq (f16), W2h (f16), b1e (f32) ----------------
__global__ void build_w_kernel(const float* __restrict__ W1,
                               const float* __restrict__ W2,
                               const float* __restrict__ b1,
                               _Float16* __restrict__ Wpq,
                               _Float16* __restrict__ W2h,
                               float* __restrict__ b1e) {
    int t = blockIdx.x * blockDim.x + threadIdx.x;   // 0 .. 16383
    if (t < H * D) {
        int h = t >> 7, k = t & 127;
        float wa = W1[h * 384 + k];
        float wb = W1[h * 384 + 128 + k];
        float wc = W1[h * 384 + 256 + k];
        Wpq[h * 128 + k]         = (_Float16)(wa + wc);
        Wpq[(128 + h) * 128 + k] = (_Float16)(wb - wc);
    }
    if (t < 64 * H) W2h[t] = (_Float16)W2[t];
    if (t < 256)    b1e[t] = (t < 128) ? b1[t] : 0.f;
}

// ---------------- kernel 1: PQ = f16( F0 @ Wpq^T + b1e ) via f16 MFMA ----------------
__global__ __launch_bounds__(64) void pq_mfma_kernel(const float* __restrict__ F0,
                                                     const _Float16* __restrict__ Wpq,
                                                     const float* __restrict__ b1e,
                                                     _Float16* __restrict__ PQ) {
    int r0 = blockIdx.x * 16;        // F0 row base
    int cb = blockIdx.y * 64;        // output col base
    int lane = threadIdx.x;
    int lp = lane & 15, lg = lane >> 4;

    f16x8 af[4];
    const float* fr = F0 + (size_t)(r0 + lp) * D;
#pragma unroll
    for (int ks = 0; ks < 4; ++ks) {
        float4 a0 = *(const float4*)(fr + ks * 32 + lg * 8);
        float4 a1 = *(const float4*)(fr + ks * 32 + lg * 8 + 4);
        f16x8 v;
        v[0] = (_Float16)a0.x; v[1] = (_Float16)a0.y;
        v[2] = (_Float16)a0.z; v[3] = (_Float16)a0.w;
        v[4] = (_Float16)a1.x; v[5] = (_Float16)a1.y;
        v[6] = (_Float16)a1.z; v[7] = (_Float16)a1.w;
        af[ks] = v;
    }

#pragma unroll
    for (int ct = 0; ct < 4; ++ct) {
        int col = cb + ct * 16 + lp;
        const _Float16* wrow = Wpq + (size_t)col * 128;
        f32x4 acc = 0.f;
#pragma unroll
        for (int ks = 0; ks < 4; ++ks) {
            f16x8 bf = *(const f16x8*)(wrow + ks * 32 + lg * 8);
            acc = __builtin_amdgcn_mfma_f32_16x16x32_f16(af[ks], bf, acc, 0, 0, 0);
        }
        float b1v = b1e[col];
#pragma unroll
        for (int e = 0; e < 4; ++e) {
            int row = r0 + lg * 4 + e;
            PQ[(size_t)row * 256 + col] = (_Float16)(acc[e] + b1v);
        }
    }
}

// ---------------- kernel 2: fused pair MLP, f16 MFMA ----------------
// No LDS: PQ is L2-resident (2 MB); P-row reads are 16-lane broadcasts.
// launch_bounds(256,3) -> ~170 VGPR budget so W2 fragments stay register-resident.
__global__ __launch_bounds__(256, 3) void pair_mfma_kernel(
        const _Float16* __restrict__ PQ,
        const _Float16* __restrict__ W2h,
        const float* __restrict__ b2, const float* __restrict__ W3,
        const float* __restrict__ b3v, const int* __restrict__ mask,
        float* __restrict__ out) {
    int b  = blockIdx.z;
    int i0 = blockIdx.y * IC;
    int j0 = blockIdx.x * JT;
    int tid  = threadIdx.x;
    int lane = tid & 63;
    int w    = tid >> 6;          // wave 0..3
    int lg   = lane >> 4;         // k-slice group 0..3
    int lp   = lane & 15;         // pair col / o row-within-group

    // W2 fragments: w2f[g][c] = row o=g*16+lp, k = c*32 + lg*8 .. +7  (64 VGPRs, resident)
    F8 w2f[4][4];
#pragma unroll
    for (int g = 0; g < 4; ++g)
#pragma unroll
        for (int c = 0; c < 4; ++c)
            w2f[g][c].u = *(const uint4*)(W2h + (size_t)(g * 16 + lp) * 128 + c * 32 + lg * 8);

    // Q fragments: lane's pair j = j0 + w*16 + lp
    int j = j0 + w * 16 + lp;
    F8 qf[4];
    {
        const _Float16* qrow = PQ + ((size_t)(b * N) + j) * 256 + 128;
#pragma unroll
        for (int c = 0; c < 4; ++c)
            qf[c].u = *(const uint4*)(qrow + c * 32 + lg * 8);
    }

    // epilogue constants: lane's o indices = g*16 + lg*4 + {0..3}
    f32x4 b2v[4], w3v[4];
#pragma unroll
    for (int g = 0; g < 4; ++g) {
        b2v[g] = *(const f32x4*)(b2 + g * 16 + lg * 4);
        w3v[g] = *(const f32x4*)(W3 + g * 16 + lg * 4);
    }
    float b3s = b3v[0];
    int   mj  = mask[b * N + j];
    const f32x4 z4 = 0.f;
    const f16x8 zh = (f16x8)(_Float16)0;

    const _Float16* Prow = PQ + ((size_t)(b * N) + i0) * 256;   // P half: cols 0..127
    const int* mrow = mask + b * N + i0;
    size_t outrow = ((size_t)(b * N) + i0) * N + j0 + w * 16 + lp;

    for (int ii = 0; ii < IC; ii += 2) {
        f32x4 acc0[4], acc1[4];
#pragma unroll
        for (int g = 0; g < 4; ++g) { acc0[g] = 0.f; acc1[g] = 0.f; }

#pragma unroll
        for (int c = 0; c < 4; ++c) {
            F8 ph0, ph1;
            ph0.u = *(const uint4*)(Prow + (size_t)ii * 256 + c * 32 + lg * 8);
            ph1.u = *(const uint4*)(Prow + (size_t)(ii + 1) * 256 + c * 32 + lg * 8);
            f16x8 hv0 = __builtin_elementwise_max(ph0.f + qf[c].f, zh);
            f16x8 hv1 = __builtin_elementwise_max(ph1.f + qf[c].f, zh);
#pragma unroll
            for (int g = 0; g < 4; ++g) {
                acc0[g] = __builtin_amdgcn_mfma_f32_16x16x32_f16(w2f[g][c].f, hv0,
                                                                 acc0[g], 0, 0, 0);
                acc1[g] = __builtin_amdgcn_mfma_f32_16x16x32_f16(w2f[g][c].f, hv1,
                                                                 acc1[g], 0, 0, 0);
            }
        }

        // packed-f32 epilogue for both i's
        f32x4 lr40 = 0.f, lr41 = 0.f;
#pragma unroll
        for (int g = 0; g < 4; ++g) {
            f32x4 t0 = __builtin_elementwise_max(acc0[g] + b2v[g], z4);
            f32x4 t1 = __builtin_elementwise_max(acc1[g] + b2v[g], z4);
            lr40 = __builtin_elementwise_fma(t0, w3v[g], lr40);
            lr41 = __builtin_elementwise_fma(t1, w3v[g], lr41);
        }
        float lr0 = (lr40.x + lr40.y) + (lr40.z + lr40.w);
        float lr1 = (lr41.x + lr41.y) + (lr41.z + lr41.w);
        lr0 += __shfl_xor(lr0, 16);
        lr0 += __shfl_xor(lr0, 32);
        lr1 += __shfl_xor(lr1, 16);
        lr1 += __shfl_xor(lr1, 32);

        float logit0 = lr0 + b3s;
        float logit1 = lr1 + b3s;
        bool  m0 = (mrow[ii] != 0)     && (mj != 0);
        bool  m1 = (mrow[ii + 1] != 0) && (mj != 0);
        float v0 = m0 ? 1.f / (1.f + __expf(-logit0)) : 0.f;
        float v1 = m1 ? 1.f / (1.f + __expf(-logit1)) : 0.f;

        if (lane < 16) {
            out[outrow + (size_t)ii * N]       = v0;
            out[outrow + (size_t)(ii + 1) * N] = v1;
        }
    }
}

extern "C" void kernel_launch(void* const* d_in, const int* in_sizes, int n_in,
                              void* d_out, int out_size, void* d_ws, size_t ws_size,
                              hipStream_t stream) {
    const float* F0  = (const float*)d_in[0];
    const int*   msk = (const int*)  d_in[1];
    const float* W1  = (const float*)d_in[2];
    const float* b1  = (const float*)d_in[3];
    const float* W2  = (const float*)d_in[4];
    const float* b2  = (const float*)d_in[5];
    const float* W3  = (const float*)d_in[6];
    const float* b3  = (const float*)d_in[7];
    float* out = (float*)d_out;

    char* ws = (char*)d_ws;
    _Float16* PQ  = (_Float16*)ws;                    // 2 MB
    _Float16* Wpq = (_Float16*)(ws + (2u << 20));     // 64 KB
    _Float16* W2h = (_Float16*)(ws + (2u << 20) + (64u << 10));  // 16 KB
    float*    b1e = (float*)   (ws + (2u << 20) + (80u << 10));  // 1 KB

    build_w_kernel<<<64, 256, 0, stream>>>(W1, W2, b1, Wpq, W2h, b1e);
    pq_mfma_kernel<<<dim3(B * N / 16, 4), 64, 0, stream>>>(F0, Wpq, b1e, PQ);
    pair_mfma_kernel<<<dim3(N / JT, N / IC, B), 256, 0, stream>>>(
        PQ, W2h, b2, W3, b3, msk, out);
}

// Round 7
// 61.113 us; speedup vs baseline: 1.3457x; 1.3457x over previous
//
#include <hip/hip_runtime.h>

#define B 8
#define N 512
#define D 128
#define H 128
#define IC 16     // i-rows per block (pair kernel)
#define JT 64     // j-cols per block (4 waves x 16)

typedef __attribute__((ext_vector_type(8))) _Float16 f16x8;
typedef __attribute__((ext_vector_type(4))) float f32x4;

union F8 { uint4 u; f16x8 f; };

// ---------------- kernel 0: build Wpq (f16), W2h (f16), b1e (f32) ----------------
__global__ void build_w_kernel(const float* __restrict__ W1,
                               const float* __restrict__ W2,
                               const float* __restrict__ b1,
                               _Float16* __restrict__ Wpq,
                               _Float16* __restrict__ W2h,
                               float* __restrict__ b1e) {
    int t = blockIdx.x * blockDim.x + threadIdx.x;   // 0 .. 16383
    if (t < H * D) {
        int h = t >> 7, k = t & 127;
        float wa = W1[h * 384 + k];
        float wb = W1[h * 384 + 128 + k];
        float wc = W1[h * 384 + 256 + k];
        Wpq[h * 128 + k]         = (_Float16)(wa + wc);
        Wpq[(128 + h) * 128 + k] = (_Float16)(wb - wc);
    }
    if (t < 64 * H) W2h[t] = (_Float16)W2[t];
    if (t < 256)    b1e[t] = (t < 128) ? b1[t] : 0.f;
}

// ---------------- kernel 1: PQ = f16( F0 @ Wpq^T + b1e ) via f16 MFMA ----------------
__global__ __launch_bounds__(64) void pq_mfma_kernel(const float* __restrict__ F0,
                                                     const _Float16* __restrict__ Wpq,
                                                     const float* __restrict__ b1e,
                                                     _Float16* __restrict__ PQ) {
    int r0 = blockIdx.x * 16;        // F0 row base
    int cb = blockIdx.y * 64;        // output col base
    int lane = threadIdx.x;
    int lp = lane & 15, lg = lane >> 4;

    f16x8 af[4];
    const float* fr = F0 + (size_t)(r0 + lp) * D;
#pragma unroll
    for (int ks = 0; ks < 4; ++ks) {
        float4 a0 = *(const float4*)(fr + ks * 32 + lg * 8);
        float4 a1 = *(const float4*)(fr + ks * 32 + lg * 8 + 4);
        f16x8 v;
        v[0] = (_Float16)a0.x; v[1] = (_Float16)a0.y;
        v[2] = (_Float16)a0.z; v[3] = (_Float16)a0.w;
        v[4] = (_Float16)a1.x; v[5] = (_Float16)a1.y;
        v[6] = (_Float16)a1.z; v[7] = (_Float16)a1.w;
        af[ks] = v;
    }

#pragma unroll
    for (int ct = 0; ct < 4; ++ct) {
        int col = cb + ct * 16 + lp;
        const _Float16* wrow = Wpq + (size_t)col * 128;
        f32x4 acc = 0.f;
#pragma unroll
        for (int ks = 0; ks < 4; ++ks) {
            f16x8 bf = *(const f16x8*)(wrow + ks * 32 + lg * 8);
            acc = __builtin_amdgcn_mfma_f32_16x16x32_f16(af[ks], bf, acc, 0, 0, 0);
        }
        float b1v = b1e[col];
#pragma unroll
        for (int e = 0; e < 4; ++e) {
            int row = r0 + lg * 4 + e;
            PQ[(size_t)row * 256 + col] = (_Float16)(acc[e] + b1v);
        }
    }
}

// ---------------- kernel 2: fused pair MLP, f16 MFMA, ii-unroll x2 ----------------
__global__ __launch_bounds__(256) void pair_mfma_kernel(
        const _Float16* __restrict__ PQ,
        const _Float16* __restrict__ W2h,
        const float* __restrict__ b2, const float* __restrict__ W3,
        const float* __restrict__ b3v, const int* __restrict__ mask,
        float* __restrict__ out) {
    int b  = blockIdx.z;
    int i0 = blockIdx.y * IC;
    int j0 = blockIdx.x * JT;
    int tid  = threadIdx.x;
    int lane = tid & 63;
    int w    = tid >> 6;          // wave 0..3
    int lg   = lane >> 4;         // k-slice group 0..3
    int lp   = lane & 15;         // pair col / o row-within-group

    __shared__ uint4 Pl[IC][16];  // P rows as f16: [row][16B chunk]
    __shared__ int   mI[IC];

    {
        // stage P halves of PQ rows i0..i0+15 (16 rows x 16 uint4 = 256 loads)
        int r = tid >> 4, c = tid & 15;
        Pl[r][c] = *(const uint4*)(PQ + ((size_t)(b * N) + i0 + r) * 256 + c * 8);
        if (tid < IC) mI[tid] = mask[b * N + i0 + tid];
    }
    __syncthreads();

    // W2 fragments: w2f[g][c] = row o=g*16+lp, k = c*32 + lg*8 .. +7  (resident)
    F8 w2f[4][4];
#pragma unroll
    for (int g = 0; g < 4; ++g)
#pragma unroll
        for (int c = 0; c < 4; ++c)
            w2f[g][c].u = *(const uint4*)(W2h + (size_t)(g * 16 + lp) * 128 + c * 32 + lg * 8);

    // Q fragments: lane's pair j = j0 + w*16 + lp
    int j = j0 + w * 16 + lp;
    F8 qf[4];
    {
        const _Float16* qrow = PQ + ((size_t)(b * N) + j) * 256 + 128;
#pragma unroll
        for (int c = 0; c < 4; ++c)
            qf[c].u = *(const uint4*)(qrow + c * 32 + lg * 8);
    }

    // epilogue constants: lane's o indices = g*16 + lg*4 + {0..3}
    f32x4 b2v[4], w3v[4];
#pragma unroll
    for (int g = 0; g < 4; ++g) {
        b2v[g] = *(const f32x4*)(b2 + g * 16 + lg * 4);
        w3v[g] = *(const f32x4*)(W3 + g * 16 + lg * 4);
    }
    float b3s = b3v[0];
    int   mj  = mask[b * N + j];
    const f32x4 z4 = 0.f;
    const f16x8 zh = (f16x8)(_Float16)0;

    size_t outrow = ((size_t)(b * N) + i0) * N + j0 + w * 16 + lp;

    for (int ii = 0; ii < IC; ii += 2) {
        f32x4 acc0[4], acc1[4];
#pragma unroll
        for (int g = 0; g < 4; ++g) { acc0[g] = 0.f; acc1[g] = 0.f; }

#pragma unroll
        for (int c = 0; c < 4; ++c) {
            F8 ph0, ph1;
            ph0.u = Pl[ii][c * 4 + lg];
            ph1.u = Pl[ii + 1][c * 4 + lg];
            f16x8 hv0 = __builtin_elementwise_max(ph0.f + qf[c].f, zh);
            f16x8 hv1 = __builtin_elementwise_max(ph1.f + qf[c].f, zh);
#pragma unroll
            for (int g = 0; g < 4; ++g) {
                acc0[g] = __builtin_amdgcn_mfma_f32_16x16x32_f16(w2f[g][c].f, hv0,
                                                                 acc0[g], 0, 0, 0);
                acc1[g] = __builtin_amdgcn_mfma_f32_16x16x32_f16(w2f[g][c].f, hv1,
                                                                 acc1[g], 0, 0, 0);
            }
        }

        // packed-f32 epilogue for both i's
        f32x4 lr40 = 0.f, lr41 = 0.f;
#pragma unroll
        for (int g = 0; g < 4; ++g) {
            f32x4 t0 = __builtin_elementwise_max(acc0[g] + b2v[g], z4);
            f32x4 t1 = __builtin_elementwise_max(acc1[g] + b2v[g], z4);
            lr40 = __builtin_elementwise_fma(t0, w3v[g], lr40);
            lr41 = __builtin_elementwise_fma(t1, w3v[g], lr41);
        }
        float lr0 = (lr40.x + lr40.y) + (lr40.z + lr40.w);
        float lr1 = (lr41.x + lr41.y) + (lr41.z + lr41.w);
        lr0 += __shfl_xor(lr0, 16);
        lr0 += __shfl_xor(lr0, 32);
        lr1 += __shfl_xor(lr1, 16);
        lr1 += __shfl_xor(lr1, 32);

        float logit0 = lr0 + b3s;
        float logit1 = lr1 + b3s;
        bool  m0 = (mI[ii] != 0)     && (mj != 0);
        bool  m1 = (mI[ii + 1] != 0) && (mj != 0);
        float v0 = m0 ? 1.f / (1.f + __expf(-logit0)) : 0.f;
        float v1 = m1 ? 1.f / (1.f + __expf(-logit1)) : 0.f;

        if (lane < 16) {
            out[outrow + (size_t)ii * N]       = v0;
            out[outrow + (size_t)(ii + 1) * N] = v1;
        }
    }
}

extern "C" void kernel_launch(void* const* d_in, const int* in_sizes, int n_in,
                              void* d_out, int out_size, void* d_ws, size_t ws_size,
                              hipStream_t stream) {
    const float* F0  = (const float*)d_in[0];
    const int*   msk = (const int*)  d_in[1];
    const float* W1  = (const float*)d_in[2];
    const float* b1  = (const float*)d_in[3];
    const float* W2  = (const float*)d_in[4];
    const float* b2  = (const float*)d_in[5];
    const float* W3  = (const float*)d_in[6];
    const float* b3  = (const float*)d_in[7];
    float* out = (float*)d_out;

    char* ws = (char*)d_ws;
    _Float16* PQ  = (_Float16*)ws;                    // 2 MB
    _Float16* Wpq = (_Float16*)(ws + (2u << 20));     // 64 KB
    _Float16* W2h = (_Float16*)(ws + (2u << 20) + (64u << 10));  // 16 KB
    float*    b1e = (float*)   (ws + (2u << 20) + (80u << 10));  // 1 KB

    build_w_kernel<<<64, 256, 0, stream>>>(W1, W2, b1, Wpq, W2h, b1e);
    pq_mfma_kernel<<<dim3(B * N / 16, 4), 64, 0, stream>>>(F0, Wpq, b1e, PQ);
    pair_mfma_kernel<<<dim3(N / JT, N / IC, B), 256, 0, stream>>>(
        PQ, W2h, b2, W3, b3, msk, out);
}